// Round 2
// baseline (829.266 us; speedup 1.0000x reference)
//
#include <hip/hip_runtime.h>
#include <math.h>

// Workspace layout (4-byte words):
#define W2OFF  0        // 8192 floats: W2[e][d] = sum_o key[e][o]*Wq[o][d]
#define B2OFF  8192     // 8 floats:    b2[e]    = sum_d bq[d]*key[e][d]
#define SCOFF  8200     // 512 floats:  score sums [batch][e]
#define AUXOFF 8712     // 1 float:     sum of w*log(w+1e-9)
#define TKOFF  8713     // 64 ints:     per-batch completion tickets
#define GTOFF  8777     // 1 int:       global (batch-winner) ticket
#define CNTOFF 8778     // 8 ints:      expert usage counts
#define ZTOT   586      // words to zero starting at SCOFF

// ---------------- k01: W2 = key@Wq, b2 = bq.key, zero accumulators ----------------
__global__ __launch_bounds__(256) void k01_prep(const float* __restrict__ Wq,
                                                const float* __restrict__ key,
                                                const float* __restrict__ bq,
                                                float* __restrict__ ws) {
    __shared__ __attribute__((aligned(16))) float keyl[8 * 1024];  // 32 KB
    __shared__ float part[256 * 8];                                // 8 KB
    int tid = threadIdx.x;
    int blk = blockIdx.x;

    if (blk == 0) {
        #pragma unroll
        for (int k = 0; k < 3; ++k) {
            int i = tid + 256 * k;
            if (i < ZTOT) ws[SCOFF + i] = 0.0f;
        }
    }

    float4* kl4 = (float4*)keyl;
    const float4* kg4 = (const float4*)key;
    #pragma unroll
    for (int k = 0; k < 8; ++k) kl4[tid + 256 * k] = kg4[tid + 256 * k];
    __syncthreads();

    // W2 slice: block owns 16 output columns d; 16 o-groups of 64.
    int dl = tid & 15;
    int og = tid >> 4;
    int d  = blk * 16 + dl;
    float acc[8];
    #pragma unroll
    for (int e = 0; e < 8; ++e) acc[e] = 0.0f;
    for (int oo = 0; oo < 64; ++oo) {
        int o = og * 64 + oo;
        float wv = Wq[o * 1024 + d];
        #pragma unroll
        for (int e = 0; e < 8; ++e) acc[e] += keyl[e * 1024 + o] * wv;
    }
    #pragma unroll
    for (int e = 0; e < 8; ++e) part[tid * 8 + e] = acc[e];
    __syncthreads();
    if (tid < 128) {
        int dl2 = tid >> 3, e = tid & 7;
        float s = 0.0f;
        #pragma unroll
        for (int g = 0; g < 16; ++g) s += part[(g * 16 + dl2) * 8 + e];
        ws[W2OFF + e * 1024 + blk * 16 + dl2] = s;
    }

    // block 0 additionally computes b2 using the LDS-staged key
    if (blk == 0) {
        __syncthreads();
        float p[8];
        #pragma unroll
        for (int e = 0; e < 8; ++e) p[e] = 0.0f;
        #pragma unroll
        for (int k = 0; k < 4; ++k) {
            int d2 = tid + 256 * k;
            float bv = bq[d2];
            #pragma unroll
            for (int e = 0; e < 8; ++e) p[e] += bv * keyl[e * 1024 + d2];
        }
        #pragma unroll
        for (int e = 0; e < 8; ++e) part[tid * 8 + e] = p[e];
        __syncthreads();
        if (tid < 8) {
            float s = 0.0f;
            for (int k = 0; k < 256; ++k) s += part[k * 8 + tid];
            ws[B2OFF + tid] = s;
        }
    }
}

__device__ __forceinline__ void top2_of8(const float* v, int& i1, int& i2) {
    i1 = 0; float b1 = v[0];
    #pragma unroll
    for (int e = 1; e < 8; ++e) if (v[e] > b1) { b1 = v[e]; i1 = e; }
    i2 = -1; float b2 = -3.4e38f;
    #pragma unroll
    for (int e = 0; e < 8; ++e) if (e != i1 && v[e] > b2) { b2 = v[e]; i2 = e; }
}

// ---------------- k2: stream x, softmax, score sums; last block per batch
//                     finalizes mask/indices; last winner writes loss ----------------
// 1024 blocks x 256 thr; block = 64 consecutive tokens of one batch.
// LDS = 32 KB (W2) + 8 KB (transpose scratch) = 40 KB -> 4 blocks/CU.
__global__ __launch_bounds__(256, 4) void k2_all(const float* __restrict__ x,
                                                 float* __restrict__ ws,
                                                 float* __restrict__ out) {
    __shared__ __attribute__((aligned(16))) float w2l[8 * 1024];    // 32 KB
    __shared__ __attribute__((aligned(16))) float part[4 * 64 * 8]; // 8 KB per-wave [64][8]

    int tid  = threadIdx.x;
    int blk  = blockIdx.x;
    int lane = tid & 63;
    int w    = tid >> 6;
    int batch = blk >> 4;
    int tb    = blk * 64;
    int e = lane >> 3, r = lane & 7;

    float4* wl4 = (float4*)w2l;
    const float4* wg4 = (const float4*)(ws + W2OFF);
    #pragma unroll
    for (int k = 0; k < 8; ++k) wl4[tid + 256 * k] = wg4[tid + 256 * k];
    float b2v = ws[B2OFF + e];
    __syncthreads();

    const float4* x4 = (const float4*)x;
    float* pw = part + w * 512;
    const float scale = 0.03125f;  // 1024^-0.5
    float sc_acc = 0.0f, aux_acc = 0.0f;

    for (int p = 0; p < 4; ++p) {
        int lt0 = w * 16 + p * 4;
        int t0  = tb + lt0;
        float acc[4][8];
        #pragma unroll
        for (int j = 0; j < 4; ++j)
            #pragma unroll
            for (int ee = 0; ee < 8; ++ee) acc[j][ee] = 0.0f;

        #pragma unroll
        for (int i = 0; i < 4; ++i) {
            float4 xr[4];
            #pragma unroll
            for (int j = 0; j < 4; ++j)
                xr[j] = x4[(size_t)(t0 + j) * 256 + i * 64 + lane];
            #pragma unroll
            for (int ee = 0; ee < 8; ++ee) {
                float4 w4 = wl4[ee * 256 + i * 64 + lane];
                #pragma unroll
                for (int j = 0; j < 4; ++j)
                    acc[j][ee] += w4.x * xr[j].x + w4.y * xr[j].y +
                                  w4.z * xr[j].z + w4.w * xr[j].w;
            }
        }

        #pragma unroll
        for (int j = 0; j < 4; ++j) {
            // wave-internal transpose: [lane][8] -> per-lane (e, r-slice) sums
            float4* pw4 = (float4*)(pw + lane * 8);
            pw4[0] = make_float4(acc[j][0], acc[j][1], acc[j][2], acc[j][3]);
            pw4[1] = make_float4(acc[j][4], acc[j][5], acc[j][6], acc[j][7]);
            float s = 0.0f;
            #pragma unroll
            for (int m = 0; m < 8; ++m) s += pw[(r + m * 8) * 8 + e];
            s += __shfl_xor(s, 1);
            s += __shfl_xor(s, 2);
            s += __shfl_xor(s, 4);
            // every lane now holds token (t0+j)'s raw score for its own e
            float sv = (s + b2v) * scale;
            float mx = sv;
            mx = fmaxf(mx, __shfl_xor(mx, 8));
            mx = fmaxf(mx, __shfl_xor(mx, 16));
            mx = fmaxf(mx, __shfl_xor(mx, 32));
            float ex = expf(sv - mx);
            float sm = ex;
            sm += __shfl_xor(sm, 8);
            sm += __shfl_xor(sm, 16);
            sm += __shfl_xor(sm, 32);
            float wgt = ex / sm;
            sc_acc  += wgt;                          // 8 identical copies across r
            aux_acc += wgt * logf(wgt + 1e-9f);      // ditto
        }
    }

    if (r == 0) atomicAdd(&ws[SCOFF + batch * 8 + e], sc_acc);
    #pragma unroll
    for (int mk = 1; mk <= 32; mk <<= 1) aux_acc += __shfl_xor(aux_acc, mk);
    if (lane == 0) atomicAdd(&ws[AUXOFF], aux_acc * 0.125f);  // /8 copies

    // ---- completion ticket: last of 16 blocks per batch finalizes ----
    __syncthreads();             // barrier drains all waves' vmem (incl. atomics)
    int* pflag = (int*)part;     // part is dead now; reuse 4 bytes
    if (tid == 0) {
        __threadfence();
        int old = atomicAdd((int*)ws + TKOFF + batch, 1);
        pflag[0] = (old == 15) ? 1 : 0;
    }
    __syncthreads();
    if (pflag[0] == 0) return;

    __threadfence();
    float v[8];
    #pragma unroll
    for (int ee = 0; ee < 8; ++ee)
        v[ee] = __hip_atomic_load(&ws[SCOFF + batch * 8 + ee],
                                  __ATOMIC_ACQUIRE, __HIP_MEMORY_SCOPE_AGENT);
    int i1, i2;
    top2_of8(v, i1, i2);
    float4 mA = make_float4(i1 == 0 || i2 == 0 ? 1.f : 0.f,
                            i1 == 1 || i2 == 1 ? 1.f : 0.f,
                            i1 == 2 || i2 == 2 ? 1.f : 0.f,
                            i1 == 3 || i2 == 3 ? 1.f : 0.f);
    float4 mB = make_float4(i1 == 4 || i2 == 4 ? 1.f : 0.f,
                            i1 == 5 || i2 == 5 ? 1.f : 0.f,
                            i1 == 6 || i2 == 6 ? 1.f : 0.f,
                            i1 == 7 || i2 == 7 ? 1.f : 0.f);
    float4* o4 = (float4*)out;
    int base = batch * 1024;
    #pragma unroll
    for (int t = 0; t < 4; ++t) {
        int token = base + t * 256 + tid;
        o4[token * 2]     = mA;
        o4[token * 2 + 1] = mB;
    }
    if (tid == 0) {
        out[524288 + batch * 2]     = (float)i1;
        out[524288 + batch * 2 + 1] = (float)i2;
        atomicAdd((int*)ws + CNTOFF + i1, 1);
        atomicAdd((int*)ws + CNTOFF + i2, 1);
        __threadfence();
        int g = atomicAdd((int*)ws + GTOFF, 1);
        if (g == 63) {   // all 64 batch-winners done => all 1024 blocks done
            __threadfence();
            float kl = 0.0f;
            #pragma unroll
            for (int ee = 0; ee < 8; ++ee) {
                int c = __hip_atomic_load((int*)ws + CNTOFF + ee,
                                          __ATOMIC_ACQUIRE, __HIP_MEMORY_SCOPE_AGENT);
                float usage = (float)c / 64.0f;
                kl += 0.125f * (logf(0.125f) - logf(usage));
            }
            kl *= 0.125f;  // / E (batchmean)
            float aux = __hip_atomic_load(&ws[AUXOFF],
                                          __ATOMIC_ACQUIRE, __HIP_MEMORY_SCOPE_AGENT)
                        / 524288.0f;
            out[524416] = 1e-3f * kl + 1e-3f * aux;
        }
    }
}

extern "C" void kernel_launch(void* const* d_in, const int* in_sizes, int n_in,
                              void* d_out, int out_size, void* d_ws, size_t ws_size,
                              hipStream_t stream) {
    const float* x   = (const float*)d_in[0];
    const float* Wq  = (const float*)d_in[1];
    const float* bq  = (const float*)d_in[2];
    const float* key = (const float*)d_in[3];
    float* out = (float*)d_out;
    float* ws  = (float*)d_ws;

    k01_prep<<<64,   256, 0, stream>>>(Wq, key, bq, ws);
    k2_all  <<<1024, 256, 0, stream>>>(x, ws, out);
}

// Round 3
// 564.398 us; speedup vs baseline: 1.4693x; 1.4693x over previous
//
#include <hip/hip_runtime.h>
#include <math.h>

// Workspace layout (4-byte words):
#define W2OFF  0        // 8192 floats: W2[e][d] = sum_o key[e][o]*Wq[o][d]
#define B2OFF  8192     // 8 floats:    b2[e]    = sum_d bq[d]*key[e][d]
#define SCOFF  8200     // 512 floats:  score sums [batch][e]
#define AUXOFF 8712     // 1 float:     sum of w*log(w+1e-9)
#define TKOFF  8713     // 64 ints:     per-batch completion tickets
#define GTOFF  8777     // 1 int:       global (batch-winner) ticket
#define CNTOFF 8778     // 8 ints:      expert usage counts
#define ZTOT   586      // words to zero starting at SCOFF

// ---------------- k01: W2 = key@Wq, b2 = bq.key, zero accumulators ----------------
__global__ __launch_bounds__(256) void k01_prep(const float* __restrict__ Wq,
                                                const float* __restrict__ key,
                                                const float* __restrict__ bq,
                                                float* __restrict__ ws) {
    __shared__ __attribute__((aligned(16))) float keyl[8 * 1024];  // 32 KB
    __shared__ float part[256 * 8];                                // 8 KB
    int tid = threadIdx.x;
    int blk = blockIdx.x;

    if (blk == 0) {
        #pragma unroll
        for (int k = 0; k < 3; ++k) {
            int i = tid + 256 * k;
            if (i < ZTOT) ws[SCOFF + i] = 0.0f;
        }
    }

    float4* kl4 = (float4*)keyl;
    const float4* kg4 = (const float4*)key;
    #pragma unroll
    for (int k = 0; k < 8; ++k) kl4[tid + 256 * k] = kg4[tid + 256 * k];
    __syncthreads();

    // W2 slice: block owns 16 output columns d; 16 o-groups of 64.
    int dl = tid & 15;
    int og = tid >> 4;
    int d  = blk * 16 + dl;
    float acc[8];
    #pragma unroll
    for (int e = 0; e < 8; ++e) acc[e] = 0.0f;
    for (int oo = 0; oo < 64; ++oo) {
        int o = og * 64 + oo;
        float wv = Wq[o * 1024 + d];
        #pragma unroll
        for (int e = 0; e < 8; ++e) acc[e] += keyl[e * 1024 + o] * wv;
    }
    #pragma unroll
    for (int e = 0; e < 8; ++e) part[tid * 8 + e] = acc[e];
    __syncthreads();
    if (tid < 128) {
        int dl2 = tid >> 3, e = tid & 7;
        float s = 0.0f;
        #pragma unroll
        for (int g = 0; g < 16; ++g) s += part[(g * 16 + dl2) * 8 + e];
        ws[W2OFF + e * 1024 + blk * 16 + dl2] = s;
    }

    // block 0 additionally computes b2 using the LDS-staged key
    if (blk == 0) {
        __syncthreads();
        float p[8];
        #pragma unroll
        for (int e = 0; e < 8; ++e) p[e] = 0.0f;
        #pragma unroll
        for (int k = 0; k < 4; ++k) {
            int d2 = tid + 256 * k;
            float bv = bq[d2];
            #pragma unroll
            for (int e = 0; e < 8; ++e) p[e] += bv * keyl[e * 1024 + d2];
        }
        #pragma unroll
        for (int e = 0; e < 8; ++e) part[tid * 8 + e] = p[e];
        __syncthreads();
        if (tid < 8) {
            float s = 0.0f;
            for (int k = 0; k < 256; ++k) s += part[k * 8 + tid];
            ws[B2OFF + tid] = s;
        }
    }
}

__device__ __forceinline__ void top2_of8(const float* v, int& i1, int& i2) {
    i1 = 0; float b1 = v[0];
    #pragma unroll
    for (int e = 1; e < 8; ++e) if (v[e] > b1) { b1 = v[e]; i1 = e; }
    i2 = -1; float b2 = -3.4e38f;
    #pragma unroll
    for (int e = 0; e < 8; ++e) if (e != i1 && v[e] > b2) { b2 = v[e]; i2 = e; }
}

// ---------------- k2: stream x, softmax, score sums; last block per batch
//                     finalizes mask/indices; last winner writes loss ----------------
// 1024 blocks x 256 thr; block = 64 consecutive tokens of one batch.
// NOTE: no min-waves arg in launch_bounds — R2 showed (256,4) forces VGPR=64
// and spills acc[4][8] to scratch (264 MB writes, 575 us). Default alloc is fine.
__global__ __launch_bounds__(256) void k2_all(const float* __restrict__ x,
                                              float* __restrict__ ws,
                                              float* __restrict__ out) {
    __shared__ __attribute__((aligned(16))) float w2l[8 * 1024];    // 32 KB
    __shared__ __attribute__((aligned(16))) float part[4 * 64 * 8]; // 8 KB per-wave [64][8]

    int tid  = threadIdx.x;
    int blk  = blockIdx.x;
    int lane = tid & 63;
    int w    = tid >> 6;
    int batch = blk >> 4;
    int tb    = blk * 64;
    int e = lane >> 3, r = lane & 7;

    float4* wl4 = (float4*)w2l;
    const float4* wg4 = (const float4*)(ws + W2OFF);
    #pragma unroll
    for (int k = 0; k < 8; ++k) wl4[tid + 256 * k] = wg4[tid + 256 * k];
    float b2v = ws[B2OFF + e];
    __syncthreads();

    const float4* x4 = (const float4*)x;
    float* pw = part + w * 512;
    const float scale = 0.03125f;  // 1024^-0.5
    float sc_acc = 0.0f, aux_acc = 0.0f;

    for (int p = 0; p < 4; ++p) {
        int lt0 = w * 16 + p * 4;
        int t0  = tb + lt0;
        float acc[4][8];
        #pragma unroll
        for (int j = 0; j < 4; ++j)
            #pragma unroll
            for (int ee = 0; ee < 8; ++ee) acc[j][ee] = 0.0f;

        #pragma unroll
        for (int i = 0; i < 4; ++i) {
            float4 xr[4];
            #pragma unroll
            for (int j = 0; j < 4; ++j)
                xr[j] = x4[(size_t)(t0 + j) * 256 + i * 64 + lane];
            #pragma unroll
            for (int ee = 0; ee < 8; ++ee) {
                float4 w4 = wl4[ee * 256 + i * 64 + lane];
                #pragma unroll
                for (int j = 0; j < 4; ++j)
                    acc[j][ee] += w4.x * xr[j].x + w4.y * xr[j].y +
                                  w4.z * xr[j].z + w4.w * xr[j].w;
            }
        }

        #pragma unroll
        for (int j = 0; j < 4; ++j) {
            // wave-internal transpose: [lane][8] -> per-lane (e, r-slice) sums
            float4* pw4 = (float4*)(pw + lane * 8);
            pw4[0] = make_float4(acc[j][0], acc[j][1], acc[j][2], acc[j][3]);
            pw4[1] = make_float4(acc[j][4], acc[j][5], acc[j][6], acc[j][7]);
            float s = 0.0f;
            #pragma unroll
            for (int m = 0; m < 8; ++m) s += pw[(r + m * 8) * 8 + e];
            s += __shfl_xor(s, 1);
            s += __shfl_xor(s, 2);
            s += __shfl_xor(s, 4);
            // every lane now holds token (t0+j)'s raw score for its own e
            float sv = (s + b2v) * scale;
            float mx = sv;
            mx = fmaxf(mx, __shfl_xor(mx, 8));
            mx = fmaxf(mx, __shfl_xor(mx, 16));
            mx = fmaxf(mx, __shfl_xor(mx, 32));
            float ex = expf(sv - mx);
            float sm = ex;
            sm += __shfl_xor(sm, 8);
            sm += __shfl_xor(sm, 16);
            sm += __shfl_xor(sm, 32);
            float wgt = ex / sm;
            sc_acc  += wgt;                          // 8 identical copies across r
            aux_acc += wgt * logf(wgt + 1e-9f);      // ditto
        }
    }

    if (r == 0) atomicAdd(&ws[SCOFF + batch * 8 + e], sc_acc);
    #pragma unroll
    for (int mk = 1; mk <= 32; mk <<= 1) aux_acc += __shfl_xor(aux_acc, mk);
    if (lane == 0) atomicAdd(&ws[AUXOFF], aux_acc * 0.125f);  // /8 copies

    // ---- completion ticket: last of 16 blocks per batch finalizes ----
    __syncthreads();             // barrier drains all waves' vmem (incl. atomics)
    int* pflag = (int*)part;     // part is dead now; reuse 4 bytes
    if (tid == 0) {
        __threadfence();
        int old = atomicAdd((int*)ws + TKOFF + batch, 1);
        pflag[0] = (old == 15) ? 1 : 0;
    }
    __syncthreads();
    if (pflag[0] == 0) return;

    __threadfence();
    float v[8];
    #pragma unroll
    for (int ee = 0; ee < 8; ++ee)
        v[ee] = __hip_atomic_load(&ws[SCOFF + batch * 8 + ee],
                                  __ATOMIC_ACQUIRE, __HIP_MEMORY_SCOPE_AGENT);
    int i1, i2;
    top2_of8(v, i1, i2);
    float4 mA = make_float4(i1 == 0 || i2 == 0 ? 1.f : 0.f,
                            i1 == 1 || i2 == 1 ? 1.f : 0.f,
                            i1 == 2 || i2 == 2 ? 1.f : 0.f,
                            i1 == 3 || i2 == 3 ? 1.f : 0.f);
    float4 mB = make_float4(i1 == 4 || i2 == 4 ? 1.f : 0.f,
                            i1 == 5 || i2 == 5 ? 1.f : 0.f,
                            i1 == 6 || i2 == 6 ? 1.f : 0.f,
                            i1 == 7 || i2 == 7 ? 1.f : 0.f);
    float4* o4 = (float4*)out;
    int base = batch * 1024;
    #pragma unroll
    for (int t = 0; t < 4; ++t) {
        int token = base + t * 256 + tid;
        o4[token * 2]     = mA;
        o4[token * 2 + 1] = mB;
    }
    if (tid == 0) {
        out[524288 + batch * 2]     = (float)i1;
        out[524288 + batch * 2 + 1] = (float)i2;
        atomicAdd((int*)ws + CNTOFF + i1, 1);
        atomicAdd((int*)ws + CNTOFF + i2, 1);
        __threadfence();
        int g = atomicAdd((int*)ws + GTOFF, 1);
        if (g == 63) {   // all 64 batch-winners done => all 1024 blocks done
            __threadfence();
            float kl = 0.0f;
            #pragma unroll
            for (int ee = 0; ee < 8; ++ee) {
                int c = __hip_atomic_load((int*)ws + CNTOFF + ee,
                                          __ATOMIC_ACQUIRE, __HIP_MEMORY_SCOPE_AGENT);
                float usage = (float)c / 64.0f;
                kl += 0.125f * (logf(0.125f) - logf(usage));
            }
            kl *= 0.125f;  // / E (batchmean)
            float aux = __hip_atomic_load(&ws[AUXOFF],
                                          __ATOMIC_ACQUIRE, __HIP_MEMORY_SCOPE_AGENT)
                        / 524288.0f;
            out[524416] = 1e-3f * kl + 1e-3f * aux;
        }
    }
}

extern "C" void kernel_launch(void* const* d_in, const int* in_sizes, int n_in,
                              void* d_out, int out_size, void* d_ws, size_t ws_size,
                              hipStream_t stream) {
    const float* x   = (const float*)d_in[0];
    const float* Wq  = (const float*)d_in[1];
    const float* bq  = (const float*)d_in[2];
    const float* key = (const float*)d_in[3];
    float* out = (float*)d_out;
    float* ws  = (float*)d_ws;

    k01_prep<<<64,   256, 0, stream>>>(Wq, key, bq, ws);
    k2_all  <<<1024, 256, 0, stream>>>(x, ws, out);
}

// Round 4
// 410.123 us; speedup vs baseline: 2.0220x; 1.3762x over previous
//
#include <hip/hip_runtime.h>
#include <math.h>

// Workspace layout (4-byte words):
#define W2OFF  0        // 8192 floats: W2[e][d] = sum_o key[e][o]*Wq[o][d]
#define B2OFF  8192     // 8 floats:    b2[e]    = sum_d bq[d]*key[e][d]
#define SCOFF  8200     // 512 floats:  score sums [batch][e]
#define AUXOFF 8712     // 1 float:     sum of w*log(w+1e-9)
#define ZTOT   513      // words to zero starting at SCOFF

// ---------------- k01: W2 = key@Wq, b2 = bq.key, zero accumulators ----------------
__global__ __launch_bounds__(256) void k01_prep(const float* __restrict__ Wq,
                                                const float* __restrict__ key,
                                                const float* __restrict__ bq,
                                                float* __restrict__ ws) {
    __shared__ __attribute__((aligned(16))) float keyl[8 * 1024];  // 32 KB
    __shared__ float part[256 * 8];                                // 8 KB
    int tid = threadIdx.x;
    int blk = blockIdx.x;

    if (blk == 0) {
        #pragma unroll
        for (int k = 0; k < 3; ++k) {
            int i = tid + 256 * k;
            if (i < ZTOT) ws[SCOFF + i] = 0.0f;
        }
    }

    float4* kl4 = (float4*)keyl;
    const float4* kg4 = (const float4*)key;
    #pragma unroll
    for (int k = 0; k < 8; ++k) kl4[tid + 256 * k] = kg4[tid + 256 * k];
    __syncthreads();

    // W2 slice: block owns 16 output columns d; 16 o-groups of 64.
    int dl = tid & 15;
    int og = tid >> 4;
    int d  = blk * 16 + dl;
    float acc[8];
    #pragma unroll
    for (int e = 0; e < 8; ++e) acc[e] = 0.0f;
    for (int oo = 0; oo < 64; ++oo) {
        int o = og * 64 + oo;
        float wv = Wq[o * 1024 + d];
        #pragma unroll
        for (int e = 0; e < 8; ++e) acc[e] += keyl[e * 1024 + o] * wv;
    }
    #pragma unroll
    for (int e = 0; e < 8; ++e) part[tid * 8 + e] = acc[e];
    __syncthreads();
    if (tid < 128) {
        int dl2 = tid >> 3, e = tid & 7;
        float s = 0.0f;
        #pragma unroll
        for (int g = 0; g < 16; ++g) s += part[(g * 16 + dl2) * 8 + e];
        ws[W2OFF + e * 1024 + blk * 16 + dl2] = s;
    }

    // block 0 additionally computes b2 using the LDS-staged key
    if (blk == 0) {
        __syncthreads();
        float p[8];
        #pragma unroll
        for (int e = 0; e < 8; ++e) p[e] = 0.0f;
        #pragma unroll
        for (int k = 0; k < 4; ++k) {
            int d2 = tid + 256 * k;
            float bv = bq[d2];
            #pragma unroll
            for (int e = 0; e < 8; ++e) p[e] += bv * keyl[e * 1024 + d2];
        }
        #pragma unroll
        for (int e = 0; e < 8; ++e) part[tid * 8 + e] = p[e];
        __syncthreads();
        if (tid < 8) {
            float s = 0.0f;
            for (int k = 0; k < 256; ++k) s += part[k * 8 + tid];
            ws[B2OFF + tid] = s;
        }
    }
}

// ---------------- k2: stream x -> per-batch score sums + aux. NO fences. ----------------
// 1024 blocks x 256 thr; block = 64 consecutive tokens of one batch.
// LDS = 32 KB (W2) + 8 KB (swizzled transpose scratch) = 40 KB -> 4 blocks/CU.
// Transpose scratch layout: value of (src_lane, expert c) at pw[c*64 + (src_lane ^ (c<<3))]
//   -> every ds_write_b32 / ds_read_b32 is <=2-way bank-aliased (free on CDNA4).
__global__ __launch_bounds__(256) void k2_main(const float* __restrict__ x,
                                               float* __restrict__ ws) {
    __shared__ __attribute__((aligned(16))) float w2l[8 * 1024];    // 32 KB
    __shared__ __attribute__((aligned(16))) float part[4 * 64 * 8]; // 8 KB, per-wave [8][64]

    int tid  = threadIdx.x;
    int blk  = blockIdx.x;
    int lane = tid & 63;
    int w    = tid >> 6;
    int batch = blk >> 4;
    int tb    = blk * 64;
    int e = lane & 7;       // expert owned after transpose (softmax = cheap masks 1/2/4)
    int r = lane >> 3;      // reduction slice (sum = masks 8/16/32)

    float4* wl4 = (float4*)w2l;
    const float4* wg4 = (const float4*)(ws + W2OFF);
    #pragma unroll
    for (int k = 0; k < 8; ++k) wl4[tid + 256 * k] = wg4[tid + 256 * k];
    float b2v = ws[B2OFF + e];
    __syncthreads();

    const float4* x4 = (const float4*)x;
    float* pw = part + w * 512;
    const float scale = 0.03125f;  // 1024^-0.5
    float sc_acc = 0.0f, aux_acc = 0.0f;

    for (int p = 0; p < 4; ++p) {
        int lt0 = w * 16 + p * 4;
        int t0  = tb + lt0;
        float acc[4][8];
        #pragma unroll
        for (int j = 0; j < 4; ++j)
            #pragma unroll
            for (int c = 0; c < 8; ++c) acc[j][c] = 0.0f;

        #pragma unroll
        for (int i = 0; i < 4; ++i) {
            float4 xr[4];
            #pragma unroll
            for (int j = 0; j < 4; ++j)
                xr[j] = x4[(size_t)(t0 + j) * 256 + i * 64 + lane];
            #pragma unroll
            for (int c = 0; c < 8; ++c) {
                float4 w4 = wl4[c * 256 + i * 64 + lane];
                #pragma unroll
                for (int j = 0; j < 4; ++j)
                    acc[j][c] += w4.x * xr[j].x + w4.y * xr[j].y +
                                 w4.z * xr[j].z + w4.w * xr[j].w;
            }
        }

        #pragma unroll
        for (int j = 0; j < 4; ++j) {
            // swizzled wave-internal transpose (conflict-free b32 ops)
            #pragma unroll
            for (int c = 0; c < 8; ++c)
                pw[c * 64 + (lane ^ (c << 3))] = acc[j][c];
            float s = 0.0f;
            #pragma unroll
            for (int m = 0; m < 8; ++m)
                s += pw[e * 64 + ((r + 8 * m) ^ (e << 3))];
            // finish 64-way sum across r (3 cross-group shfls)
            s += __shfl_xor(s, 8);
            s += __shfl_xor(s, 16);
            s += __shfl_xor(s, 32);
            // every lane: raw score of token (t0+j) for its expert e
            float sv = (s + b2v) * scale;
            // softmax across e (cheap within-row masks)
            float mx = sv;
            mx = fmaxf(mx, __shfl_xor(mx, 1));
            mx = fmaxf(mx, __shfl_xor(mx, 2));
            mx = fmaxf(mx, __shfl_xor(mx, 4));
            float ex = expf(sv - mx);
            float sm = ex;
            sm += __shfl_xor(sm, 1);
            sm += __shfl_xor(sm, 2);
            sm += __shfl_xor(sm, 4);
            float wgt = ex / sm;
            sc_acc  += wgt;                       // replicated 8x across r
            aux_acc += wgt * logf(wgt + 1e-9f);   // ditto
        }
    }

    if (r == 0) atomicAdd(&ws[SCOFF + batch * 8 + e], sc_acc);
    #pragma unroll
    for (int mk = 1; mk <= 32; mk <<= 1) aux_acc += __shfl_xor(aux_acc, mk);
    if (lane == 0) atomicAdd(&ws[AUXOFF], aux_acc * 0.125f);  // /8 replicas
}

// ---------------- k3: top-2, mask broadcast, indices, loss ----------------
__device__ __forceinline__ void top2_of8(const float* v, int& i1, int& i2) {
    i1 = 0; float b1 = v[0];
    #pragma unroll
    for (int e = 1; e < 8; ++e) if (v[e] > b1) { b1 = v[e]; i1 = e; }
    i2 = -1; float b2 = -3.4e38f;
    #pragma unroll
    for (int e = 0; e < 8; ++e) if (e != i1 && v[e] > b2) { b2 = v[e]; i2 = e; }
}

__global__ __launch_bounds__(256) void k3_out(const float* __restrict__ ws,
                                              float* __restrict__ out) {
    int tid = threadIdx.x;
    int blk = blockIdx.x;            // 256 blocks; 4 per batch
    int batch = blk >> 2;

    float v[8];
    #pragma unroll
    for (int e = 0; e < 8; ++e) v[e] = ws[SCOFF + batch * 8 + e];
    int i1, i2;
    top2_of8(v, i1, i2);

    float m[8];
    #pragma unroll
    for (int e = 0; e < 8; ++e) m[e] = (e == i1 || e == i2) ? 1.0f : 0.0f;
    int token = blk * 256 + tid;
    float4* o4 = (float4*)out;
    o4[token * 2]     = make_float4(m[0], m[1], m[2], m[3]);
    o4[token * 2 + 1] = make_float4(m[4], m[5], m[6], m[7]);

    if (blk == 0) {
        __shared__ int cnt[8];
        if (tid < 8) cnt[tid] = 0;
        __syncthreads();
        if (tid < 64) {
            float vv[8];
            #pragma unroll
            for (int e = 0; e < 8; ++e) vv[e] = ws[SCOFF + tid * 8 + e];
            int j1, j2;
            top2_of8(vv, j1, j2);
            out[524288 + tid * 2]     = (float)j1;
            out[524288 + tid * 2 + 1] = (float)j2;
            atomicAdd(&cnt[j1], 1);
            atomicAdd(&cnt[j2], 1);
        }
        __syncthreads();
        if (tid == 0) {
            float kl = 0.0f;
            #pragma unroll
            for (int e = 0; e < 8; ++e) {
                float usage = (float)cnt[e] / 64.0f;
                kl += 0.125f * (logf(0.125f) - logf(usage));
            }
            kl *= 0.125f;  // / E (batchmean)
            float aux = ws[AUXOFF] / 524288.0f;
            out[524416] = 1e-3f * kl + 1e-3f * aux;
        }
    }
}

extern "C" void kernel_launch(void* const* d_in, const int* in_sizes, int n_in,
                              void* d_out, int out_size, void* d_ws, size_t ws_size,
                              hipStream_t stream) {
    const float* x   = (const float*)d_in[0];
    const float* Wq  = (const float*)d_in[1];
    const float* bq  = (const float*)d_in[2];
    const float* key = (const float*)d_in[3];
    float* out = (float*)d_out;
    float* ws  = (float*)d_ws;

    k01_prep<<<64,   256, 0, stream>>>(Wq, key, bq, ws);
    k2_main<<<1024, 256, 0, stream>>>(x, ws);
    k3_out <<<256,  256, 0, stream>>>(ws, out);
}

// Round 5
// 384.080 us; speedup vs baseline: 2.1591x; 1.0678x over previous
//
#include <hip/hip_runtime.h>
#include <math.h>

// Workspace layout (4-byte words):
#define W2OFF  0        // 8192 floats: W2[e][d] = sum_o key[e][o]*Wq[o][d]
#define B2OFF  8192     // 8 floats:    b2[e]    = sum_d bq[d]*key[e][d]
#define SCOFF  8200     // 512 floats:  score sums [batch][e]
#define AUXOFF 8712     // 1 float:     sum of w*log(w+1e-9)   (== SCOFF+512)
#define ZTOT   513      // words to zero starting at SCOFF

// ---------------- k01: W2 = key@Wq, b2 = bq.key, zero accumulators ----------------
__global__ __launch_bounds__(256) void k01_prep(const float* __restrict__ Wq,
                                                const float* __restrict__ key,
                                                const float* __restrict__ bq,
                                                float* __restrict__ ws) {
    __shared__ __attribute__((aligned(16))) float keyl[8 * 1024];  // 32 KB
    __shared__ float part[256 * 8];                                // 8 KB
    __shared__ float part2[64];
    int tid = threadIdx.x;
    int blk = blockIdx.x;

    // distributed zeroing: 64 blocks x 9 words covers 513
    if (tid < 9) {
        int i = blk * 9 + tid;
        if (i < ZTOT) ws[SCOFF + i] = 0.0f;
    }

    float4* kl4 = (float4*)keyl;
    const float4* kg4 = (const float4*)key;
    #pragma unroll
    for (int k = 0; k < 8; ++k) kl4[tid + 256 * k] = kg4[tid + 256 * k];
    __syncthreads();

    // W2 slice: block owns 16 output columns d; 16 o-groups of 64.
    int dl = tid & 15;
    int og = tid >> 4;
    int d  = blk * 16 + dl;
    float acc[8];
    #pragma unroll
    for (int e = 0; e < 8; ++e) acc[e] = 0.0f;
    for (int oo = 0; oo < 64; ++oo) {
        int o = og * 64 + oo;
        float wv = Wq[o * 1024 + d];
        #pragma unroll
        for (int e = 0; e < 8; ++e) acc[e] += keyl[e * 1024 + o] * wv;
    }
    #pragma unroll
    for (int e = 0; e < 8; ++e) part[tid * 8 + e] = acc[e];
    __syncthreads();
    if (tid < 128) {
        int dl2 = tid >> 3, e = tid & 7;
        float s = 0.0f;
        #pragma unroll
        for (int g = 0; g < 16; ++g) s += part[(g * 16 + dl2) * 8 + e];
        ws[W2OFF + e * 1024 + blk * 16 + dl2] = s;
    }

    // block 0 additionally computes b2 using the LDS-staged key (tree reduce)
    if (blk == 0) {
        __syncthreads();
        float p[8];
        #pragma unroll
        for (int e = 0; e < 8; ++e) p[e] = 0.0f;
        #pragma unroll
        for (int k = 0; k < 4; ++k) {
            int d2 = tid + 256 * k;
            float bv = bq[d2];
            #pragma unroll
            for (int e = 0; e < 8; ++e) p[e] += bv * keyl[e * 1024 + d2];
        }
        #pragma unroll
        for (int e = 0; e < 8; ++e) part[tid * 8 + e] = p[e];
        __syncthreads();
        if (tid < 64) {                 // stage 1: 64 threads sum 32 rows each
            int e = tid & 7, g = tid >> 3;
            float s = 0.0f;
            #pragma unroll
            for (int k = 0; k < 32; ++k) s += part[(g * 32 + k) * 8 + e];
            part2[g * 8 + e] = s;
        }
        __syncthreads();
        if (tid < 8) {                  // stage 2: 8 threads sum 8 partials
            float s = 0.0f;
            #pragma unroll
            for (int g = 0; g < 8; ++g) s += part2[g * 8 + tid];
            ws[B2OFF + tid] = s;
        }
    }
}

// ---------------- k2: stream x -> raw scores -> phase-B softmax + sums ----------------
// 1024 blocks x 256 thr; block = 64 consecutive tokens of one batch.
// In-loop: swizzled conflict-free transpose + 8 LDS reads + 3 CHEAP shfl (masks 1/2/4).
// Softmax/exp/log deferred to 64-thread phase B (once per token, lane-local).
// LDS = 32 KB (W2) + 8 KB (transpose) + 2 KB (sraw) = 42 KB -> 3 blocks/CU.
__global__ __launch_bounds__(256) void k2_main(const float* __restrict__ x,
                                               float* __restrict__ ws) {
    __shared__ __attribute__((aligned(16))) float w2l[8 * 1024];    // 32 KB
    __shared__ __attribute__((aligned(16))) float part[4 * 64 * 8]; // 8 KB per-wave [8][64]
    __shared__ __attribute__((aligned(16))) float sraw[64 * 8];     // 2 KB raw scores

    int tid  = threadIdx.x;
    int blk  = blockIdx.x;
    int lane = tid & 63;
    int w    = tid >> 6;
    int batch = blk >> 4;
    int tb    = blk * 64;
    int e = lane >> 3;      // expert owned after transpose
    int r = lane & 7;       // reduction slice -> cheap shfl masks 1/2/4

    float4* wl4 = (float4*)w2l;
    const float4* wg4 = (const float4*)(ws + W2OFF);
    #pragma unroll
    for (int k = 0; k < 8; ++k) wl4[tid + 256 * k] = wg4[tid + 256 * k];
    __syncthreads();

    const float4* x4 = (const float4*)x;
    float* pw = part + w * 512;

    for (int p = 0; p < 4; ++p) {
        int lt0 = w * 16 + p * 4;
        int t0  = tb + lt0;
        float acc[4][8];
        #pragma unroll
        for (int j = 0; j < 4; ++j)
            #pragma unroll
            for (int c = 0; c < 8; ++c) acc[j][c] = 0.0f;

        #pragma unroll
        for (int i = 0; i < 4; ++i) {
            float4 xr[4];
            #pragma unroll
            for (int j = 0; j < 4; ++j)
                xr[j] = x4[(size_t)(t0 + j) * 256 + i * 64 + lane];
            #pragma unroll
            for (int c = 0; c < 8; ++c) {
                float4 w4 = wl4[c * 256 + i * 64 + lane];
                #pragma unroll
                for (int j = 0; j < 4; ++j)
                    acc[j][c] += w4.x * xr[j].x + w4.y * xr[j].y +
                                 w4.z * xr[j].z + w4.w * xr[j].w;
            }
        }

        #pragma unroll
        for (int j = 0; j < 4; ++j) {
            // swizzled wave-internal transpose: <=2-way bank alias on write & read
            #pragma unroll
            for (int c = 0; c < 8; ++c)
                pw[c * 64 + (lane ^ (c << 3))] = acc[j][c];
            float s = 0.0f;
            #pragma unroll
            for (int m = 0; m < 8; ++m)
                s += pw[e * 64 + ((r + 8 * m) ^ (e << 3))];
            s += __shfl_xor(s, 1);
            s += __shfl_xor(s, 2);
            s += __shfl_xor(s, 4);
            if (r == 0) sraw[(lt0 + j) * 8 + e] = s;  // raw dot, pre-bias/scale
        }
    }
    __syncthreads();

    // Phase B: 64 threads, one token each, lane-local softmax (no shuffles until reduce)
    if (tid < 64) {
        int t = tid;
        float sv[8];
        #pragma unroll
        for (int k = 0; k < 8; ++k) {        // rotated reads to spread banks
            int c = (t + k) & 7;
            sv[c] = sraw[t * 8 + c];
        }
        const float scale = 0.03125f;        // 1024^-0.5
        #pragma unroll
        for (int c = 0; c < 8; ++c) sv[c] = (sv[c] + ws[B2OFF + c]) * scale;
        float mx = sv[0];
        #pragma unroll
        for (int c = 1; c < 8; ++c) mx = fmaxf(mx, sv[c]);
        float wgt[8], sm = 0.0f;
        #pragma unroll
        for (int c = 0; c < 8; ++c) { wgt[c] = expf(sv[c] - mx); sm += wgt[c]; }
        float inv = 1.0f / sm;
        float aux = 0.0f;
        #pragma unroll
        for (int c = 0; c < 8; ++c) {
            wgt[c] *= inv;
            aux += wgt[c] * logf(wgt[c] + 1e-9f);
        }
        // block score-sum reduce via the same swizzled transpose (these 64 = wave 0)
        #pragma unroll
        for (int c = 0; c < 8; ++c)
            part[c * 64 + (t ^ (c << 3))] = wgt[c];
        int e2 = t >> 3, r2 = t & 7;
        float s2 = 0.0f;
        #pragma unroll
        for (int m = 0; m < 8; ++m)
            s2 += part[e2 * 64 + ((r2 + 8 * m) ^ (e2 << 3))];
        s2 += __shfl_xor(s2, 1);
        s2 += __shfl_xor(s2, 2);
        s2 += __shfl_xor(s2, 4);
        if (r2 == 0) atomicAdd(&ws[SCOFF + batch * 8 + e2], s2);
        #pragma unroll
        for (int mk = 1; mk <= 32; mk <<= 1) aux += __shfl_xor(aux, mk);
        if (t == 0) atomicAdd(&ws[AUXOFF], aux);
    }
}

// ---------------- k3: top-2, mask broadcast, indices, loss ----------------
__device__ __forceinline__ void top2_of8(const float* v, int& i1, int& i2) {
    i1 = 0; float b1 = v[0];
    #pragma unroll
    for (int e = 1; e < 8; ++e) if (v[e] > b1) { b1 = v[e]; i1 = e; }
    i2 = -1; float b2 = -3.4e38f;
    #pragma unroll
    for (int e = 0; e < 8; ++e) if (e != i1 && v[e] > b2) { b2 = v[e]; i2 = e; }
}

__global__ __launch_bounds__(256) void k3_out(const float* __restrict__ ws,
                                              float* __restrict__ out) {
    int tid = threadIdx.x;
    int blk = blockIdx.x;            // 256 blocks; 4 per batch
    int batch = blk >> 2;

    float v[8];
    #pragma unroll
    for (int e = 0; e < 8; ++e) v[e] = ws[SCOFF + batch * 8 + e];
    int i1, i2;
    top2_of8(v, i1, i2);

    float m[8];
    #pragma unroll
    for (int e = 0; e < 8; ++e) m[e] = (e == i1 || e == i2) ? 1.0f : 0.0f;
    int token = blk * 256 + tid;
    float4* o4 = (float4*)out;
    o4[token * 2]     = make_float4(m[0], m[1], m[2], m[3]);
    o4[token * 2 + 1] = make_float4(m[4], m[5], m[6], m[7]);

    if (blk == 0) {
        __shared__ int cnt[8];
        if (tid < 8) cnt[tid] = 0;
        __syncthreads();
        if (tid < 64) {
            float vv[8];
            #pragma unroll
            for (int e = 0; e < 8; ++e) vv[e] = ws[SCOFF + tid * 8 + e];
            int j1, j2;
            top2_of8(vv, j1, j2);
            out[524288 + tid * 2]     = (float)j1;
            out[524288 + tid * 2 + 1] = (float)j2;
            atomicAdd(&cnt[j1], 1);
            atomicAdd(&cnt[j2], 1);
        }
        __syncthreads();
        if (tid == 0) {
            float kl = 0.0f;
            #pragma unroll
            for (int e = 0; e < 8; ++e) {
                float usage = (float)cnt[e] / 64.0f;
                kl += 0.125f * (logf(0.125f) - logf(usage));
            }
            kl *= 0.125f;  // / E (batchmean)
            float aux = ws[AUXOFF] / 524288.0f;
            out[524416] = 1e-3f * kl + 1e-3f * aux;
        }
    }
}

extern "C" void kernel_launch(void* const* d_in, const int* in_sizes, int n_in,
                              void* d_out, int out_size, void* d_ws, size_t ws_size,
                              hipStream_t stream) {
    const float* x   = (const float*)d_in[0];
    const float* Wq  = (const float*)d_in[1];
    const float* bq  = (const float*)d_in[2];
    const float* key = (const float*)d_in[3];
    float* out = (float*)d_out;
    float* ws  = (float*)d_ws;

    k01_prep<<<64,   256, 0, stream>>>(Wq, key, bq, ws);
    k2_main<<<1024, 256, 0, stream>>>(x, ws);
    k3_out <<<256,  256, 0, stream>>>(ws, out);
}